// Round 3
// baseline (21257.108 us; speedup 1.0000x reference)
//
#include <hip/hip_runtime.h>
#include <math.h>

#define T_LEN 512
#define B_SZ  32
#define I_DIM 512
#define H_DIM 1024
#define NBLK  256
#define HS    (B_SZ * H_DIM)   // 32768 floats per state snapshot

typedef float fx4 __attribute__((ext_vector_type(4)));   // nontemporal-compatible

// ---------------------------------------------------------------------------
// bias_combine
// ---------------------------------------------------------------------------
__global__ void bias_combine(const float* __restrict__ b_ii, const float* __restrict__ b_hi,
                             const float* __restrict__ b_ci, const float* __restrict__ b_if,
                             const float* __restrict__ b_hf, const float* __restrict__ b_cf,
                             const float* __restrict__ b_ic, const float* __restrict__ b_hc,
                             const float* __restrict__ b_io, const float* __restrict__ b_ho,
                             const float* __restrict__ b_cyo, float* __restrict__ bias4) {
    int r = blockIdx.x * 256 + threadIdx.x;
    if (r < H_DIM) {
        bias4[r]        = b_ii[r] + b_hi[r] + b_ci[r];
        bias4[1024 + r] = b_if[r] + b_hf[r] + b_cf[r];
        bias4[2048 + r] = b_ic[r] + b_hc[r];
        bias4[3072 + r] = b_io[r] + b_ho[r] + b_cyo[r];
    }
}

// ---------------------------------------------------------------------------
// pregemm: C[n][m] = sum_k A[m][k]*W[nloc][k] + bias4[n]   (TRANSPOSED output:
// leading dim M, so the scan's per-step reads are coalesced over m.)
// M = Tc*32, K = 512, N = 4096. 128x128 tile, BK=16, 256 thr, 8x8/thread.
// ---------------------------------------------------------------------------
#define BM 128
#define BN 128
#define BK 16
__global__ __launch_bounds__(256) void pregemm(const float* __restrict__ A,
                                               const float* __restrict__ w0,
                                               const float* __restrict__ w1,
                                               const float* __restrict__ w2,
                                               const float* __restrict__ w3,
                                               const float* __restrict__ bias4,
                                               float* __restrict__ C, int M) {
    __shared__ float As[BK][BM + 4];
    __shared__ float Bs[BK][BN + 4];
    int tid = threadIdx.x;
    int n0 = blockIdx.y * BN;
    const float* W = (n0 < 1024) ? w0 : (n0 < 2048) ? w1 : (n0 < 3072) ? w2 : w3;
    int nloc = n0 & 1023;

    int lr = tid >> 2;
    int lk = (tid & 3) << 2;
    const float* Arow = A + (size_t)(blockIdx.x * BM + lr) * I_DIM + lk;
    const float* Brow = W + (size_t)(nloc + lr) * I_DIM + lk;

    float acc[8][8];
#pragma unroll
    for (int i = 0; i < 8; ++i)
#pragma unroll
        for (int j = 0; j < 8; ++j) acc[i][j] = 0.f;

    int mth = (tid >> 4) << 3;
    int nth = (tid & 15) << 3;

    for (int kt = 0; kt < I_DIM; kt += BK) {
        float4 a0 = *(const float4*)(Arow + kt);
        float4 a1 = *(const float4*)(Arow + 64 * I_DIM + kt);
        float4 b0 = *(const float4*)(Brow + kt);
        float4 b1 = *(const float4*)(Brow + 64 * I_DIM + kt);
        __syncthreads();
        As[lk + 0][lr] = a0.x; As[lk + 1][lr] = a0.y; As[lk + 2][lr] = a0.z; As[lk + 3][lr] = a0.w;
        As[lk + 0][lr + 64] = a1.x; As[lk + 1][lr + 64] = a1.y; As[lk + 2][lr + 64] = a1.z; As[lk + 3][lr + 64] = a1.w;
        Bs[lk + 0][lr] = b0.x; Bs[lk + 1][lr] = b0.y; Bs[lk + 2][lr] = b0.z; Bs[lk + 3][lr] = b0.w;
        Bs[lk + 0][lr + 64] = b1.x; Bs[lk + 1][lr + 64] = b1.y; Bs[lk + 2][lr + 64] = b1.z; Bs[lk + 3][lr + 64] = b1.w;
        __syncthreads();
#pragma unroll
        for (int j = 0; j < BK; ++j) {
            float am[8], bn[8];
            *(float4*)&am[0] = *(const float4*)&As[j][mth];
            *(float4*)&am[4] = *(const float4*)&As[j][mth + 4];
            *(float4*)&bn[0] = *(const float4*)&Bs[j][nth];
            *(float4*)&bn[4] = *(const float4*)&Bs[j][nth + 4];
#pragma unroll
            for (int ii = 0; ii < 8; ++ii)
#pragma unroll
                for (int jj = 0; jj < 8; ++jj) acc[ii][jj] += am[ii] * bn[jj];
        }
    }

    int mbase = blockIdx.x * BM + mth;
#pragma unroll
    for (int jj = 0; jj < 8; ++jj) {
        int n = n0 + nth + jj;
        float bn = bias4[n];
        float* crow = C + (size_t)n * M + mbase;
        fx4 v0, v1;
        v0.x = acc[0][jj] + bn; v0.y = acc[1][jj] + bn;
        v0.z = acc[2][jj] + bn; v0.w = acc[3][jj] + bn;
        v1.x = acc[4][jj] + bn; v1.y = acc[5][jj] + bn;
        v1.z = acc[6][jj] + bn; v1.w = acc[7][jj] + bn;
        __builtin_nontemporal_store(v0, (fx4*)crow);
        __builtin_nontemporal_store(v1, (fx4*)(crow + 4));
    }
}

// ---------------------------------------------------------------------------
// helpers
// ---------------------------------------------------------------------------
__device__ __forceinline__ float sigm(float x) { return 1.f / (1.f + __expf(-x)); }
__device__ __forceinline__ float tanh_fast(float x) { return 2.f / (1.f + __expf(-2.f * x)) - 1.f; }

__device__ __forceinline__ void agent_store(float* p, float v) {
    __hip_atomic_store(p, v, __ATOMIC_RELAXED, __HIP_MEMORY_SCOPE_AGENT);
}

// two-level arrival barrier (thread 0 only); no cache-flush fences.
__device__ __forceinline__ void arrive_wait(unsigned* grp, unsigned* master,
                                            int grpid, unsigned bidx) {
    unsigned old = __hip_atomic_fetch_add(&grp[grpid * 16], 1u,
                                          __ATOMIC_RELAXED, __HIP_MEMORY_SCOPE_AGENT);
    if (old == bidx * 32u + 31u)
        __hip_atomic_fetch_add(master, 1u, __ATOMIC_RELAXED, __HIP_MEMORY_SCOPE_AGENT);
    while (__hip_atomic_load(master, __ATOMIC_RELAXED, __HIP_MEMORY_SCOPE_AGENT)
           < (bidx + 1u) * 8u)
        __builtin_amdgcn_s_sleep(1);
}

// ---------------------------------------------------------------------------
// Persistent cooperative scan. 256 blocks x 512 thr (8 waves); block owns
// rows r0..r0+3. Wave wv owns k-slice [wv*128, wv*128+128).
//
// Pipe-split weight streams:
//  * Only w_hi/w_hf (phase-A gs0) live in LDS (32 KB). The broadcast weight
//    reads for w_ci/w_cf (gs1), w_hc/w_ho (gs2) and w_cyo come straight from
//    global memory: each block's 80 KB slice stays hot in its XCD's L2
//    (32 blocks x 80 KB = 2.5 MB < 4 MiB), and same-address-per-half-wave
//    loads coalesce to 2 cache lines per instr -> they ride the otherwise
//    idle VMEM pipe instead of the saturated LDS pipe (was 448 b128/wave/step
//    on LDS ~ 17.9 us/CU; now 128 on LDS + ~320 cheap broadcast VMEM).
//  * Dynamic-LDS request padded to 84 KB so only 1 block fits per CU ->
//    cooperative launch keeps the exact 256-block/256-CU mapping.
//  * c-peephole dots for step t+1 computed in phase B(t) off the cy4 regs;
//    cy_lds persists own-row c; G loads issued before the phase-A k-loop.
// ---------------------------------------------------------------------------
#define SMEM_FLOATS (8192 + 6144 + 1024 + 128 + 128)
#define SMEM_BYTES  (86016)   // 84 KB requested (uses 61 KB) -> 1 block/CU

__global__ __launch_bounds__(512) void lstm_scan(
    const float* __restrict__ G,
    const float* __restrict__ h0,
    const float* __restrict__ c_init,
    const float* __restrict__ w_hi, const float* __restrict__ w_ci,
    const float* __restrict__ w_hf, const float* __restrict__ w_cf,
    const float* __restrict__ w_hc, const float* __restrict__ w_ho,
    const float* __restrict__ w_cyo,
    float* __restrict__ out,
    float* __restrict__ c_hist,
    unsigned* __restrict__ grp_ctr,
    unsigned* __restrict__ master,
    int t0, int Tc, int M)
{
    extern __shared__ float smem[];
    float* wA     = smem;             // [2][4][1024]  32 KB : w_hi(0), w_hf(1)
    float* redA   = wA + 8192;        // [8][24][32]   24 KB   (gate-slot partials)
    float* redB   = redA + 6144;      // [8][4][32]     4 KB   (cyo partials)
    float* po_lds = redB + 1024;      // [4][32]
    float* cy_lds = po_lds + 128;     // [4][32]  persistent own-row c state

    int tid = threadIdx.x;
    int blk = blockIdx.x;
    int r0 = blk * 4;
    int grpid = blk & 7;

    int wv = tid >> 6;            // 0..7 : k-split
    int lane = tid & 63;
    int half = lane >> 5;         // gate-row group
    int b = lane & 31;            // batch
    int kbase = wv * 128;

    // ---- load LDS weight slices (w_hi, w_hf only) ----
    {
        const float* srcs[2] = {w_hi, w_hf};
#pragma unroll
        for (int m = 0; m < 2; ++m) {
            const float4* s = (const float4*)(srcs[m] + (size_t)r0 * H_DIM);
            float4* d = (float4*)(wA + m * 4096);
            d[tid] = s[tid];
            d[tid + 512] = s[tid + 512];
        }
    }

    // redA slot-gate ids (layout labels, unchanged): slot0/2 consume h,
    // slot1 consumes c, slot4/5 consume h.
    int gs0 = half ? 2 : 0;       // w_hf : w_hi   (h)   -- LDS
    int gs1 = half ? 3 : 1;       // w_cf : w_ci   (c)   -- global
    int gs2 = half ? 5 : 4;       // w_ho : w_hc   (h)   -- global

    // LDS weight pointers for gs0 (kbase folded in, step-invariant)
    const float* wpk[4];
#pragma unroll
    for (int q = 0; q < 4; ++q)
        wpk[q] = wA + ((half ? 1 : 0) * 4 + q) * 1024 + kbase;

    // Global (L2-resident) weight pointers for gs1 / gs2 / cyo
    const float* m1 = half ? w_cf : w_ci;
    const float* m2 = half ? w_ho : w_hc;
    const float* wg1[4];
    const float* wg2[4];
#pragma unroll
    for (int q = 0; q < 4; ++q) {
        wg1[q] = m1 + (size_t)(r0 + q) * H_DIM + kbase;
        wg2[q] = m2 + (size_t)(r0 + q) * H_DIM + kbase;
    }
    const float* wBk0 = w_cyo + (size_t)(r0 + half * 2 + 0) * H_DIM + kbase;
    const float* wBk1 = w_cyo + (size_t)(r0 + half * 2 + 1) * H_DIM + kbase;

    // finisher mapping (threads 0..127)
    int frw = (tid >> 5) & 3;
    int fb = tid & 31;
    int fr = r0 + frw;

    __syncthreads();   // weights ready

    // ---- pre-loop: c-dots for step 0 from c_init + cy_lds init ----
    {
        const float* cb0 = c_init + (size_t)b * H_DIM + kbase;
        float ca[4];
#pragma unroll
        for (int q = 0; q < 4; ++q) ca[q] = 0.f;
#pragma unroll 4
        for (int it = 0; it < 32; ++it) {
            int k = it * 4;
            float4 c4 = *(const float4*)(cb0 + k);
#pragma unroll
            for (int q = 0; q < 4; ++q) {
                float4 w4 = *(const float4*)(wg1[q] + k);
                ca[q] += w4.x * c4.x + w4.y * c4.y + w4.z * c4.z + w4.w * c4.w;
            }
        }
#pragma unroll
        for (int q = 0; q < 4; ++q)
            redA[wv * 768 + (gs1 * 4 + q) * 32 + b] = ca[q];
        if (tid < 128)
            cy_lds[frw * 32 + fb] = c_init[(size_t)fb * H_DIM + fr];
    }

    unsigned bidx = 0;

    for (int tt = 0; tt < Tc; ++tt) {
        int t = t0 + tt;
        const float* hp = (t == 0) ? h0 : out + (size_t)(t - 1) * HS;
        float* cw = c_hist + (size_t)(tt + 1) * HS;

        // ---------------- phase A main: h-dots (gs0 from LDS, gs2 from L2) ------
        float xi = 0.f, xf = 0.f, xg = 0.f, xo = 0.f;
        if (tid < 128) {
            int m = tt * 32 + fb;
            xi = __builtin_nontemporal_load(G + (size_t)(0 * 1024 + fr) * M + m);
            xf = __builtin_nontemporal_load(G + (size_t)(1 * 1024 + fr) * M + m);
            xg = __builtin_nontemporal_load(G + (size_t)(2 * 1024 + fr) * M + m);
            xo = __builtin_nontemporal_load(G + (size_t)(3 * 1024 + fr) * M + m);
        }

        const float* hb = hp + (size_t)b * H_DIM + kbase;
        float acc[8];
#pragma unroll
        for (int j = 0; j < 8; ++j) acc[j] = 0.f;

#pragma unroll 4
        for (int it = 0; it < 32; ++it) {
            int k = it * 4;
            float4 h4 = *(const float4*)(hb + k);
#pragma unroll
            for (int q = 0; q < 4; ++q) {
                float4 w4 = *(const float4*)(wpk[q] + k);       // LDS
                acc[q] += w4.x * h4.x + w4.y * h4.y + w4.z * h4.z + w4.w * h4.w;
            }
#pragma unroll
            for (int q = 0; q < 4; ++q) {
                float4 w4 = *(const float4*)(wg2[q] + k);       // global/L2
                acc[4 + q] += w4.x * h4.x + w4.y * h4.y + w4.z * h4.z + w4.w * h4.w;
            }
        }
#pragma unroll
        for (int q = 0; q < 4; ++q) {
            redA[wv * 768 + (gs0 * 4 + q) * 32 + b] = acc[q];
            redA[wv * 768 + (gs2 * 4 + q) * 32 + b] = acc[4 + q];
        }
        __syncthreads();

        // ---------------- phase A finisher (threads 0..127) ----------------
        // gs1 slots hold c-dot partials written by phase B(t-1) / pre-loop.
        if (tid < 128) {
            float s[6];
#pragma unroll
            for (int g = 0; g < 6; ++g) {
                float v = 0.f;
#pragma unroll
                for (int k8 = 0; k8 < 8; ++k8)
                    v += redA[k8 * 768 + (g * 4 + frw) * 32 + fb];
                s[g] = v;
            }
            float iv = sigm(xi + s[0] + s[1]);
            float fv = sigm(xf + s[2] + s[3]);
            float gv = tanh_fast(xg + s[4]);
            float cold = cy_lds[frw * 32 + fb];      // own c(t-1), persisted in LDS
            float cy = fv * cold + iv * gv;
            agent_store(&cw[(size_t)fb * H_DIM + fr], cy);
            po_lds[frw * 32 + fb] = xo + s[5];
            cy_lds[frw * 32 + fb] = cy;
        }
        __syncthreads();              // drains the agent stores too

        // ---------------- barrier: cy globally visible ----------------
        if (tid == 0) arrive_wait(grp_ctr, master, grpid, bidx);
        bidx++;
        __builtin_amdgcn_fence(__ATOMIC_ACQUIRE, "workgroup");
        __syncthreads();

        // ---------------- phase B main: cyo dot + next-step c-dots (all L2) -----
        // cy4 is loaded once and feeds BOTH the w_cyo dot (this step) and the
        // w_ci/w_cf dots (next step).
        const float* cyb = cw + (size_t)b * H_DIM + kbase;
        float a0 = 0.f, a1 = 0.f;
        float ca[4];
#pragma unroll
        for (int q = 0; q < 4; ++q) ca[q] = 0.f;
#pragma unroll 4
        for (int it = 0; it < 32; ++it) {
            int k = it * 4;
            float4 cy4 = *(const float4*)(cyb + k);
            float4 w0 = *(const float4*)(wBk0 + k);             // global/L2
            float4 w1 = *(const float4*)(wBk1 + k);             // global/L2
            a0 += w0.x * cy4.x + w0.y * cy4.y + w0.z * cy4.z + w0.w * cy4.w;
            a1 += w1.x * cy4.x + w1.y * cy4.y + w1.z * cy4.z + w1.w * cy4.w;
#pragma unroll
            for (int q = 0; q < 4; ++q) {
                float4 w4 = *(const float4*)(wg1[q] + k);       // global/L2
                ca[q] += w4.x * cy4.x + w4.y * cy4.y + w4.z * cy4.z + w4.w * cy4.w;
            }
        }
        redB[wv * 128 + (half * 2 + 0) * 32 + b] = a0;
        redB[wv * 128 + (half * 2 + 1) * 32 + b] = a1;
#pragma unroll
        for (int q = 0; q < 4; ++q)
            redA[wv * 768 + (gs1 * 4 + q) * 32 + b] = ca[q];   // for step t+1
        __syncthreads();

        // ---------------- phase B finisher ----------------
        if (tid < 128) {
            float v = 0.f;
#pragma unroll
            for (int k8 = 0; k8 < 8; ++k8)
                v += redB[k8 * 128 + frw * 32 + fb];
            float o = sigm(po_lds[frw * 32 + fb] + v);
            float hy = o * tanh_fast(cy_lds[frw * 32 + fb]);
            agent_store(&out[(size_t)t * HS + (size_t)fb * H_DIM + fr], hy);
        }
        __syncthreads();

        // ---------------- barrier: h(t) globally visible ----------------
        if (tid == 0) arrive_wait(grp_ctr, master, grpid, bidx);
        bidx++;
        __builtin_amdgcn_fence(__ATOMIC_ACQUIRE, "workgroup");
        __syncthreads();
    }
}

// ---------------------------------------------------------------------------
extern "C" void kernel_launch(void* const* d_in, const int* in_sizes, int n_in,
                              void* d_out, int out_size, void* d_ws, size_t ws_size,
                              hipStream_t stream) {
    const float* X     = (const float*)d_in[0];
    const float* h0    = (const float*)d_in[1];
    const float* c0    = (const float*)d_in[2];
    const float* w_ii  = (const float*)d_in[3];
    const float* w_hi  = (const float*)d_in[4];
    const float* w_ci  = (const float*)d_in[5];
    const float* w_if  = (const float*)d_in[6];
    const float* w_hf  = (const float*)d_in[7];
    const float* w_cf  = (const float*)d_in[8];
    const float* w_ic  = (const float*)d_in[9];
    const float* w_hc  = (const float*)d_in[10];
    const float* w_io  = (const float*)d_in[11];
    const float* w_ho  = (const float*)d_in[12];
    const float* w_cyo = (const float*)d_in[13];
    const float* b_ii  = (const float*)d_in[14];
    const float* b_hi  = (const float*)d_in[15];
    const float* b_ci  = (const float*)d_in[16];
    const float* b_if  = (const float*)d_in[17];
    const float* b_hf  = (const float*)d_in[18];
    const float* b_cf  = (const float*)d_in[19];
    const float* b_ic  = (const float*)d_in[20];
    const float* b_hc  = (const float*)d_in[21];
    const float* b_io  = (const float*)d_in[22];
    const float* b_ho  = (const float*)d_in[23];
    const float* b_cyo = (const float*)d_in[24];
    float* out = (float*)d_out;

    (void)hipFuncSetAttribute((const void*)lstm_scan,
                              hipFuncAttributeMaxDynamicSharedMemorySize, SMEM_BYTES);

    // ws carve: G (4096 x M floats) | bias4 | c_hist ((Tc+1)*HS) | counters
    int Tc = 512;
    while (Tc > 8) {
        size_t need = ((size_t)Tc * 131072 + 4096 + (size_t)(Tc + 1) * HS) * 4 + 2048;
        if (need <= ws_size) break;
        Tc >>= 1;
    }
    int M = Tc * 32;

    float* G      = (float*)d_ws;
    float* bias4  = G + (size_t)Tc * 131072;
    float* c_hist = bias4 + 4096;
    unsigned* grp_ctr = (unsigned*)(c_hist + (size_t)(Tc + 1) * HS);
    unsigned* master  = grp_ctr + 256;

    bias_combine<<<4, 256, 0, stream>>>(b_ii, b_hi, b_ci, b_if, b_hf, b_cf,
                                        b_ic, b_hc, b_io, b_ho, b_cyo, bias4);

    const float* c_init = c0;
    for (int t0 = 0; t0 < T_LEN; t0 += Tc) {
        pregemm<<<dim3(M / BM, 4096 / BN), 256, 0, stream>>>(
            X + (size_t)t0 * B_SZ * I_DIM, w_ii, w_if, w_ic, w_io, bias4, G, M);
        (void)hipMemsetAsync(grp_ctr, 0, 2048, stream);

        const float* Gp = G;
        float* chp = c_hist;
        unsigned* gcp = grp_ctr;
        unsigned* mp = master;
        int t0v = t0, Tcv = Tc, Mv = M;
        void* args[] = {
            (void*)&Gp, (void*)&h0, (void*)&c_init,
            (void*)&w_hi, (void*)&w_ci, (void*)&w_hf, (void*)&w_cf,
            (void*)&w_hc, (void*)&w_ho, (void*)&w_cyo,
            (void*)&out, (void*)&chp, (void*)&gcp, (void*)&mp,
            (void*)&t0v, (void*)&Tcv, (void*)&Mv
        };
        (void)hipLaunchCooperativeKernel((const void*)lstm_scan, dim3(NBLK), dim3(512),
                                         args, SMEM_BYTES, stream);
        c_init = c_hist + (size_t)Tc * HS;
    }
}

// Round 4
// 12098.045 us; speedup vs baseline: 1.7571x; 1.7571x over previous
//
#include <hip/hip_runtime.h>
#include <math.h>

#define T_LEN 512
#define B_SZ  32
#define I_DIM 512
#define H_DIM 1024
#define NBLK  256
#define HS    (B_SZ * H_DIM)   // 32768 floats per state snapshot
#define WROW  1028             // padded LDS weight-row stride (floats): breaks 8-way bank conflict

typedef float fx4 __attribute__((ext_vector_type(4)));   // nontemporal-compatible

// ---------------------------------------------------------------------------
// bias_combine
// ---------------------------------------------------------------------------
__global__ void bias_combine(const float* __restrict__ b_ii, const float* __restrict__ b_hi,
                             const float* __restrict__ b_ci, const float* __restrict__ b_if,
                             const float* __restrict__ b_hf, const float* __restrict__ b_cf,
                             const float* __restrict__ b_ic, const float* __restrict__ b_hc,
                             const float* __restrict__ b_io, const float* __restrict__ b_ho,
                             const float* __restrict__ b_cyo, float* __restrict__ bias4) {
    int r = blockIdx.x * 256 + threadIdx.x;
    if (r < H_DIM) {
        bias4[r]        = b_ii[r] + b_hi[r] + b_ci[r];
        bias4[1024 + r] = b_if[r] + b_hf[r] + b_cf[r];
        bias4[2048 + r] = b_ic[r] + b_hc[r];
        bias4[3072 + r] = b_io[r] + b_ho[r] + b_cyo[r];
    }
}

// ---------------------------------------------------------------------------
// pregemm: C[n][m] = sum_k A[m][k]*W[nloc][k] + bias4[n]   (TRANSPOSED output)
// ---------------------------------------------------------------------------
#define BM 128
#define BN 128
#define BK 16
__global__ __launch_bounds__(256) void pregemm(const float* __restrict__ A,
                                               const float* __restrict__ w0,
                                               const float* __restrict__ w1,
                                               const float* __restrict__ w2,
                                               const float* __restrict__ w3,
                                               const float* __restrict__ bias4,
                                               float* __restrict__ C, int M) {
    __shared__ float As[BK][BM + 4];
    __shared__ float Bs[BK][BN + 4];
    int tid = threadIdx.x;
    int n0 = blockIdx.y * BN;
    const float* W = (n0 < 1024) ? w0 : (n0 < 2048) ? w1 : (n0 < 3072) ? w2 : w3;
    int nloc = n0 & 1023;

    int lr = tid >> 2;
    int lk = (tid & 3) << 2;
    const float* Arow = A + (size_t)(blockIdx.x * BM + lr) * I_DIM + lk;
    const float* Brow = W + (size_t)(nloc + lr) * I_DIM + lk;

    float acc[8][8];
#pragma unroll
    for (int i = 0; i < 8; ++i)
#pragma unroll
        for (int j = 0; j < 8; ++j) acc[i][j] = 0.f;

    int mth = (tid >> 4) << 3;
    int nth = (tid & 15) << 3;

    for (int kt = 0; kt < I_DIM; kt += BK) {
        float4 a0 = *(const float4*)(Arow + kt);
        float4 a1 = *(const float4*)(Arow + 64 * I_DIM + kt);
        float4 b0 = *(const float4*)(Brow + kt);
        float4 b1 = *(const float4*)(Brow + 64 * I_DIM + kt);
        __syncthreads();
        As[lk + 0][lr] = a0.x; As[lk + 1][lr] = a0.y; As[lk + 2][lr] = a0.z; As[lk + 3][lr] = a0.w;
        As[lk + 0][lr + 64] = a1.x; As[lk + 1][lr + 64] = a1.y; As[lk + 2][lr + 64] = a1.z; As[lk + 3][lr + 64] = a1.w;
        Bs[lk + 0][lr] = b0.x; Bs[lk + 1][lr] = b0.y; Bs[lk + 2][lr] = b0.z; Bs[lk + 3][lr] = b0.w;
        Bs[lk + 0][lr + 64] = b1.x; Bs[lk + 1][lr + 64] = b1.y; Bs[lk + 2][lr + 64] = b1.z; Bs[lk + 3][lr + 64] = b1.w;
        __syncthreads();
#pragma unroll
        for (int j = 0; j < BK; ++j) {
            float am[8], bn[8];
            *(float4*)&am[0] = *(const float4*)&As[j][mth];
            *(float4*)&am[4] = *(const float4*)&As[j][mth + 4];
            *(float4*)&bn[0] = *(const float4*)&Bs[j][nth];
            *(float4*)&bn[4] = *(const float4*)&Bs[j][nth + 4];
#pragma unroll
            for (int ii = 0; ii < 8; ++ii)
#pragma unroll
                for (int jj = 0; jj < 8; ++jj) acc[ii][jj] += am[ii] * bn[jj];
        }
    }

    int mbase = blockIdx.x * BM + mth;
#pragma unroll
    for (int jj = 0; jj < 8; ++jj) {
        int n = n0 + nth + jj;
        float bn = bias4[n];
        float* crow = C + (size_t)n * M + mbase;
        fx4 v0, v1;
        v0.x = acc[0][jj] + bn; v0.y = acc[1][jj] + bn;
        v0.z = acc[2][jj] + bn; v0.w = acc[3][jj] + bn;
        v1.x = acc[4][jj] + bn; v1.y = acc[5][jj] + bn;
        v1.z = acc[6][jj] + bn; v1.w = acc[7][jj] + bn;
        __builtin_nontemporal_store(v0, (fx4*)crow);
        __builtin_nontemporal_store(v1, (fx4*)(crow + 4));
    }
}

// ---------------------------------------------------------------------------
// helpers
// ---------------------------------------------------------------------------
__device__ __forceinline__ float sigm(float x) { return 1.f / (1.f + __expf(-x)); }
__device__ __forceinline__ float tanh_fast(float x) { return 2.f / (1.f + __expf(-2.f * x)) - 1.f; }

__device__ __forceinline__ void agent_store(float* p, float v) {
    __hip_atomic_store(p, v, __ATOMIC_RELAXED, __HIP_MEMORY_SCOPE_AGENT);
}

// two-level arrival barrier (thread 0 only); no cache-flush fences.
__device__ __forceinline__ void arrive_wait(unsigned* grp, unsigned* master,
                                            int grpid, unsigned bidx) {
    unsigned old = __hip_atomic_fetch_add(&grp[grpid * 16], 1u,
                                          __ATOMIC_RELAXED, __HIP_MEMORY_SCOPE_AGENT);
    if (old == bidx * 32u + 31u)
        __hip_atomic_fetch_add(master, 1u, __ATOMIC_RELAXED, __HIP_MEMORY_SCOPE_AGENT);
    while (__hip_atomic_load(master, __ATOMIC_RELAXED, __HIP_MEMORY_SCOPE_AGENT)
           < (bidx + 1u) * 8u)
        __builtin_amdgcn_s_sleep(1);
}

// ---------------------------------------------------------------------------
// Persistent cooperative scan. 256 blocks x 512 thr (8 waves); block owns
// rows r0..r0+3 of all 7 matrices (weights LDS-resident, padded rows).
// Wave wv owns k-slice [wv*128, wv*128+128).
//
// Batch-amortized lane mapping (new this round; replaces (half,b) mapping):
//   lane = (g<<3)|rml : g = bgroup 0..7 (4 batches b=g*4..g*4+3),
//                       rml = row-lane 0..7 (2 gate-rows per lane).
//   One ds_read_b128 of weights now feeds 16 FMAs (4 batches x 4 k) instead
//   of 4 -> weight LDS instrs drop 448 -> 128 per wave per step. The h/cy
//   operands come as 4 per-row global float4s per iter (L1-cached, 8x line
//   reuse); weight rows padded to WROW=1028 so the 8 row-lanes' reads are
//   <=2-way bank-aliased (free).
//   Each lane's acc is a full k-slice partial for (row, b) -> one b128 write
//   to redA/redB, no cross-lane reduce. Finisher (128 thr) sums 8 waves as
//   before (same summation tree as the verified R1 kernel).
//   ci/cf dots for step t+1 are computed in phase B(t) off the same cy4 regs
//   (redB slots 4..11 carry across the step boundary); cy_lds persists own-
//   row c; G loads prefetched before the phase-A k-loop.
// ---------------------------------------------------------------------------
#define SMEM_FLOATS (28 * WROW + 4096 + 4096 + 128 + 128)
#define SMEM_BYTES  (SMEM_FLOATS * 4)   // 148928 B -> 1 block/CU

__global__ __launch_bounds__(512) void lstm_scan(
    const float* __restrict__ G,
    const float* __restrict__ h0,
    const float* __restrict__ c_init,
    const float* __restrict__ w_hi, const float* __restrict__ w_ci,
    const float* __restrict__ w_hf, const float* __restrict__ w_cf,
    const float* __restrict__ w_hc, const float* __restrict__ w_ho,
    const float* __restrict__ w_cyo,
    float* __restrict__ out,
    float* __restrict__ c_hist,
    unsigned* __restrict__ grp_ctr,
    unsigned* __restrict__ master,
    int t0, int Tc, int M)
{
    extern __shared__ float smem[];
    float* wAB    = smem;               // 28 rows x WROW: {hi,ci,hf,cf,hc,ho}x4 + cyo x4
    float* redA   = smem + 28 * WROW;   // [8 wv][16 rm][32 b] : hi0-3,hf4-7,hc8-11,ho12-15
    float* redB   = redA + 4096;        // [8 wv][16 rm][32 b] : cyo0-3,ci4-7,cf8-11,dup12-15
    float* po_lds = redB + 4096;        // [4][32]
    float* cy_lds = po_lds + 128;       // [4][32]  persistent own-row c state

    int tid = threadIdx.x;
    int blk = blockIdx.x;
    int r0 = blk * 4;
    int grpid = blk & 7;

    int wv = tid >> 6;            // 0..7 : k-split
    int lane = tid & 63;
    int g = lane >> 3;            // bgroup: batches g*4 .. g*4+3
    int rml = lane & 7;           // row-lane
    int kbase = wv * 128;
    int b0 = g * 4;

    // ---- stage all 28 weight rows into padded LDS ----
    {
        const float* srcs[7] = {w_hi, w_ci, w_hf, w_cf, w_hc, w_ho, w_cyo};
        for (int idx = tid; idx < 28 * 256; idx += 512) {
            int rr = idx >> 8;              // 0..27
            int kk = (idx & 255) << 2;      // 0..1020
            float4 v = *(const float4*)(srcs[rr >> 2] + (size_t)(r0 + (rr & 3)) * H_DIM + kk);
            *(float4*)(wAB + rr * WROW + kk) = v;
        }
    }

    // phase-A weights: first = hi(rows0-3)/hf(rows8-11), second = hc(16-19)/ho(20-23)
    int mi1 = rml >> 2, q1 = rml & 3;
    const float* pA1 = wAB + (mi1 * 8 + q1) * WROW + kbase;
    const float* pA2 = wAB + (16 + mi1 * 4 + q1) * WROW + kbase;
    int rmA1 = mi1 * 4 + q1;        // redA slot 0..7  (hi,hf)
    int rmA2 = 8 + mi1 * 4 + q1;    // redA slot 8..15 (hc,ho)

    // phase-B weights: first = cyo(rows24-27)/ci(rows4-7), second = cf(rows12-15)
    const float* pB1 = (rml < 4) ? (wAB + (24 + rml) * WROW + kbase)
                                 : (wAB + (4 + (rml - 4)) * WROW + kbase);
    const float* pB2 = wAB + (12 + (rml & 3)) * WROW + kbase;
    int rmB1 = rml;                 // 0..3 cyo, 4..7 ci
    int rmB2 = 8 + rml;             // 8..11 cf (valid), 12..15 dup (ignored)

    // finisher mapping (threads 0..127)
    int frw = (tid >> 5) & 3;
    int fb = tid & 31;
    int fr = r0 + frw;

    __syncthreads();   // weights ready

    // ---- pre-loop: ci/cf dots of c_init (cyo slots get garbage, unused) ----
    {
        const float* cb = c_init + (size_t)b0 * H_DIM + kbase;
        float s10 = 0.f, s11 = 0.f, s12 = 0.f, s13 = 0.f;
        float s20 = 0.f, s21 = 0.f, s22 = 0.f, s23 = 0.f;
#pragma unroll 4
        for (int it = 0; it < 32; ++it) {
            int k = it * 4;
            float4 c0v = *(const float4*)(cb + 0 * H_DIM + k);
            float4 c1v = *(const float4*)(cb + 1 * H_DIM + k);
            float4 c2v = *(const float4*)(cb + 2 * H_DIM + k);
            float4 c3v = *(const float4*)(cb + 3 * H_DIM + k);
            float4 wa = *(const float4*)(pB1 + k);
            float4 wb = *(const float4*)(pB2 + k);
            s10 += wa.x * c0v.x + wa.y * c0v.y + wa.z * c0v.z + wa.w * c0v.w;
            s11 += wa.x * c1v.x + wa.y * c1v.y + wa.z * c1v.z + wa.w * c1v.w;
            s12 += wa.x * c2v.x + wa.y * c2v.y + wa.z * c2v.z + wa.w * c2v.w;
            s13 += wa.x * c3v.x + wa.y * c3v.y + wa.z * c3v.z + wa.w * c3v.w;
            s20 += wb.x * c0v.x + wb.y * c0v.y + wb.z * c0v.z + wb.w * c0v.w;
            s21 += wb.x * c1v.x + wb.y * c1v.y + wb.z * c1v.z + wb.w * c1v.w;
            s22 += wb.x * c2v.x + wb.y * c2v.y + wb.z * c2v.z + wb.w * c2v.w;
            s23 += wb.x * c3v.x + wb.y * c3v.y + wb.z * c3v.z + wb.w * c3v.w;
        }
        *(float4*)(redB + (wv * 16 + rmB1) * 32 + b0) = (float4){s10, s11, s12, s13};
        *(float4*)(redB + (wv * 16 + rmB2) * 32 + b0) = (float4){s20, s21, s22, s23};
        if (tid < 128)
            cy_lds[frw * 32 + fb] = c_init[(size_t)fb * H_DIM + fr];
    }

    unsigned bidx = 0;

    for (int tt = 0; tt < Tc; ++tt) {
        int t = t0 + tt;
        const float* hp = (t == 0) ? h0 : out + (size_t)(t - 1) * HS;
        float* cw = c_hist + (size_t)(tt + 1) * HS;

        // ---------------- phase A main: h-dots for hi/hf/hc/ho ----------------
        float xi = 0.f, xf = 0.f, xg = 0.f, xo = 0.f;
        if (tid < 128) {
            int m = tt * 32 + fb;
            xi = __builtin_nontemporal_load(G + (size_t)(0 * 1024 + fr) * M + m);
            xf = __builtin_nontemporal_load(G + (size_t)(1 * 1024 + fr) * M + m);
            xg = __builtin_nontemporal_load(G + (size_t)(2 * 1024 + fr) * M + m);
            xo = __builtin_nontemporal_load(G + (size_t)(3 * 1024 + fr) * M + m);
        }

        const float* hb = hp + (size_t)b0 * H_DIM + kbase;
        float a10 = 0.f, a11 = 0.f, a12 = 0.f, a13 = 0.f;
        float a20 = 0.f, a21 = 0.f, a22 = 0.f, a23 = 0.f;
#pragma unroll 4
        for (int it = 0; it < 32; ++it) {
            int k = it * 4;
            float4 h0v = *(const float4*)(hb + 0 * H_DIM + k);
            float4 h1v = *(const float4*)(hb + 1 * H_DIM + k);
            float4 h2v = *(const float4*)(hb + 2 * H_DIM + k);
            float4 h3v = *(const float4*)(hb + 3 * H_DIM + k);
            float4 wa = *(const float4*)(pA1 + k);
            float4 wb = *(const float4*)(pA2 + k);
            a10 += wa.x * h0v.x + wa.y * h0v.y + wa.z * h0v.z + wa.w * h0v.w;
            a11 += wa.x * h1v.x + wa.y * h1v.y + wa.z * h1v.z + wa.w * h1v.w;
            a12 += wa.x * h2v.x + wa.y * h2v.y + wa.z * h2v.z + wa.w * h2v.w;
            a13 += wa.x * h3v.x + wa.y * h3v.y + wa.z * h3v.z + wa.w * h3v.w;
            a20 += wb.x * h0v.x + wb.y * h0v.y + wb.z * h0v.z + wb.w * h0v.w;
            a21 += wb.x * h1v.x + wb.y * h1v.y + wb.z * h1v.z + wb.w * h1v.w;
            a22 += wb.x * h2v.x + wb.y * h2v.y + wb.z * h2v.z + wb.w * h2v.w;
            a23 += wb.x * h3v.x + wb.y * h3v.y + wb.z * h3v.z + wb.w * h3v.w;
        }
        *(float4*)(redA + (wv * 16 + rmA1) * 32 + b0) = (float4){a10, a11, a12, a13};
        *(float4*)(redA + (wv * 16 + rmA2) * 32 + b0) = (float4){a20, a21, a22, a23};
        __syncthreads();

        // ---------------- phase A finisher (threads 0..127) ----------------
        // redB slots 4..11 hold ci/cf partials from phase B(t-1) / pre-loop.
        if (tid < 128) {
            float shi = 0.f, shf = 0.f, shc = 0.f, sho = 0.f, sci = 0.f, scf = 0.f;
#pragma unroll
            for (int w8 = 0; w8 < 8; ++w8) {
                shi += redA[(w8 * 16 + 0 + frw) * 32 + fb];
                shf += redA[(w8 * 16 + 4 + frw) * 32 + fb];
                shc += redA[(w8 * 16 + 8 + frw) * 32 + fb];
                sho += redA[(w8 * 16 + 12 + frw) * 32 + fb];
                sci += redB[(w8 * 16 + 4 + frw) * 32 + fb];
                scf += redB[(w8 * 16 + 8 + frw) * 32 + fb];
            }
            float iv = sigm(xi + shi + sci);
            float fv = sigm(xf + shf + scf);
            float gv = tanh_fast(xg + shc);
            float cold = cy_lds[frw * 32 + fb];      // own c(t-1), persisted in LDS
            float cy = fv * cold + iv * gv;
            agent_store(&cw[(size_t)fb * H_DIM + fr], cy);
            po_lds[frw * 32 + fb] = xo + sho;
            cy_lds[frw * 32 + fb] = cy;
        }
        __syncthreads();              // drains the agent stores too

        // ---------------- barrier: cy globally visible ----------------
        if (tid == 0) arrive_wait(grp_ctr, master, grpid, bidx);
        bidx++;
        __builtin_amdgcn_fence(__ATOMIC_ACQUIRE, "workgroup");
        __syncthreads();

        // ---------------- phase B main: cyo dot + next-step ci/cf dots ----------
        const float* cyb = cw + (size_t)b0 * H_DIM + kbase;
        float b10 = 0.f, b11 = 0.f, b12 = 0.f, b13 = 0.f;
        float b20 = 0.f, b21 = 0.f, b22 = 0.f, b23 = 0.f;
#pragma unroll 4
        for (int it = 0; it < 32; ++it) {
            int k = it * 4;
            float4 c0v = *(const float4*)(cyb + 0 * H_DIM + k);
            float4 c1v = *(const float4*)(cyb + 1 * H_DIM + k);
            float4 c2v = *(const float4*)(cyb + 2 * H_DIM + k);
            float4 c3v = *(const float4*)(cyb + 3 * H_DIM + k);
            float4 wa = *(const float4*)(pB1 + k);
            float4 wb = *(const float4*)(pB2 + k);
            b10 += wa.x * c0v.x + wa.y * c0v.y + wa.z * c0v.z + wa.w * c0v.w;
            b11 += wa.x * c1v.x + wa.y * c1v.y + wa.z * c1v.z + wa.w * c1v.w;
            b12 += wa.x * c2v.x + wa.y * c2v.y + wa.z * c2v.z + wa.w * c2v.w;
            b13 += wa.x * c3v.x + wa.y * c3v.y + wa.z * c3v.z + wa.w * c3v.w;
            b20 += wb.x * c0v.x + wb.y * c0v.y + wb.z * c0v.z + wb.w * c0v.w;
            b21 += wb.x * c1v.x + wb.y * c1v.y + wb.z * c1v.z + wb.w * c1v.w;
            b22 += wb.x * c2v.x + wb.y * c2v.y + wb.z * c2v.z + wb.w * c2v.w;
            b23 += wb.x * c3v.x + wb.y * c3v.y + wb.z * c3v.z + wb.w * c3v.w;
        }
        *(float4*)(redB + (wv * 16 + rmB1) * 32 + b0) = (float4){b10, b11, b12, b13};
        *(float4*)(redB + (wv * 16 + rmB2) * 32 + b0) = (float4){b20, b21, b22, b23};
        __syncthreads();

        // ---------------- phase B finisher ----------------
        if (tid < 128) {
            float v = 0.f;
#pragma unroll
            for (int w8 = 0; w8 < 8; ++w8)
                v += redB[(w8 * 16 + frw) * 32 + fb];       // cyo slots 0..3
            float o = sigm(po_lds[frw * 32 + fb] + v);
            float hy = o * tanh_fast(cy_lds[frw * 32 + fb]);
            agent_store(&out[(size_t)t * HS + (size_t)fb * H_DIM + fr], hy);
        }
        __syncthreads();

        // ---------------- barrier: h(t) globally visible ----------------
        if (tid == 0) arrive_wait(grp_ctr, master, grpid, bidx);
        bidx++;
        __builtin_amdgcn_fence(__ATOMIC_ACQUIRE, "workgroup");
        __syncthreads();
    }
}

// ---------------------------------------------------------------------------
extern "C" void kernel_launch(void* const* d_in, const int* in_sizes, int n_in,
                              void* d_out, int out_size, void* d_ws, size_t ws_size,
                              hipStream_t stream) {
    const float* X     = (const float*)d_in[0];
    const float* h0    = (const float*)d_in[1];
    const float* c0    = (const float*)d_in[2];
    const float* w_ii  = (const float*)d_in[3];
    const float* w_hi  = (const float*)d_in[4];
    const float* w_ci  = (const float*)d_in[5];
    const float* w_if  = (const float*)d_in[6];
    const float* w_hf  = (const float*)d_in[7];
    const float* w_cf  = (const float*)d_in[8];
    const float* w_ic  = (const float*)d_in[9];
    const float* w_hc  = (const float*)d_in[10];
    const float* w_io  = (const float*)d_in[11];
    const float* w_ho  = (const float*)d_in[12];
    const float* w_cyo = (const float*)d_in[13];
    const float* b_ii  = (const float*)d_in[14];
    const float* b_hi  = (const float*)d_in[15];
    const float* b_ci  = (const float*)d_in[16];
    const float* b_if  = (const float*)d_in[17];
    const float* b_hf  = (const float*)d_in[18];
    const float* b_cf  = (const float*)d_in[19];
    const float* b_ic  = (const float*)d_in[20];
    const float* b_hc  = (const float*)d_in[21];
    const float* b_io  = (const float*)d_in[22];
    const float* b_ho  = (const float*)d_in[23];
    const float* b_cyo = (const float*)d_in[24];
    float* out = (float*)d_out;

    (void)hipFuncSetAttribute((const void*)lstm_scan,
                              hipFuncAttributeMaxDynamicSharedMemorySize, SMEM_BYTES);

    // ws carve: G (4096 x M floats) | bias4 | c_hist ((Tc+1)*HS) | counters
    int Tc = 512;
    while (Tc > 8) {
        size_t need = ((size_t)Tc * 131072 + 4096 + (size_t)(Tc + 1) * HS) * 4 + 2048;
        if (need <= ws_size) break;
        Tc >>= 1;
    }
    int M = Tc * 32;

    float* G      = (float*)d_ws;
    float* bias4  = G + (size_t)Tc * 131072;
    float* c_hist = bias4 + 4096;
    unsigned* grp_ctr = (unsigned*)(c_hist + (size_t)(Tc + 1) * HS);
    unsigned* master  = grp_ctr + 256;

    bias_combine<<<4, 256, 0, stream>>>(b_ii, b_hi, b_ci, b_if, b_hf, b_cf,
                                        b_ic, b_hc, b_io, b_ho, b_cyo, bias4);

    const float* c_init = c0;
    for (int t0 = 0; t0 < T_LEN; t0 += Tc) {
        pregemm<<<dim3(M / BM, 4096 / BN), 256, 0, stream>>>(
            X + (size_t)t0 * B_SZ * I_DIM, w_ii, w_if, w_ic, w_io, bias4, G, M);
        (void)hipMemsetAsync(grp_ctr, 0, 2048, stream);

        const float* Gp = G;
        float* chp = c_hist;
        unsigned* gcp = grp_ctr;
        unsigned* mp = master;
        int t0v = t0, Tcv = Tc, Mv = M;
        void* args[] = {
            (void*)&Gp, (void*)&h0, (void*)&c_init,
            (void*)&w_hi, (void*)&w_ci, (void*)&w_hf, (void*)&w_cf,
            (void*)&w_hc, (void*)&w_ho, (void*)&w_cyo,
            (void*)&out, (void*)&chp, (void*)&gcp, (void*)&mp,
            (void*)&t0v, (void*)&Tcv, (void*)&Mv
        };
        (void)hipLaunchCooperativeKernel((const void*)lstm_scan, dim3(NBLK), dim3(512),
                                         args, SMEM_BYTES, stream);
        c_init = c_hist + (size_t)Tc * HS;
    }
}